// Round 10
// baseline (608.675 us; speedup 1.0000x reference)
//
#include <hip/hip_runtime.h>
#include <hip/hip_fp16.h>

#define NU 100000      // N_USERS
#define NE 100000      // N_ENTITIES
#define NN 200000      // N_NODES
#define EKG 1500000
#define EPR 1500000
#define NNZI 1000000
#define D 64

#define GCN_ENT_BASE (NU * D)
#define NODE_BASE    (NN * D)

// ---- bucket partition config ----
#define KG_NB 98     // ceil(NE/1024)
#define PR_NB 196    // ceil(NN/1024)
#define IT_NB 98     // ceil(NU/1024)
#define NBALL (KG_NB + PR_NB + IT_NB)

#define KG_CAP 20480
#define PR_CAP 12288
#define IT_CAP 13312

// pass A grid: 128 groups x 13 blocks (4 KG + 4 PR + 3 IT + 2 INIT),
// round-robin interleaved so all segments are co-resident: streaming init
// fills the latency-bound multisplit's idle memory pipeline.
#define SEG_G 128
#define KG_B 512
#define KG_CHUNK 2930    // 512*2930 >= EKG
#define PR_B 512
#define PR_CHUNK 2930
#define IT_B 384
#define IT_CHUNK 2605    // 384*2605 >= NNZI
#define INIT_B 256
#define PARTA_GRID (SEG_G * 13)

// ---- fp16 pack helpers (sources fp16; all math fp32) ----
__device__ __forceinline__ uint2 f4_to_h4(float4 v) {
    __half2 a = __floats2half2_rn(v.x, v.y);
    __half2 b = __floats2half2_rn(v.z, v.w);
    uint2 r;
    r.x = *(unsigned int*)&a;
    r.y = *(unsigned int*)&b;
    return r;
}
__device__ __forceinline__ float4 h4_to_f4(unsigned int lo, unsigned int hi) {
    float2 a = __half22float2(*(__half2*)&lo);
    float2 b = __half22float2(*(__half2*)&hi);
    return make_float4(a.x, a.y, b.x, b.y);
}

// -------- pass A: multisplit (KG/PR/IT) + fused output-init segment --------
__global__ void __launch_bounds__(256) k_partA(
        const int* __restrict__ kg_head, const int* __restrict__ kg_tail,
        const int* __restrict__ kg_type,
        const int* __restrict__ pr_head, const int* __restrict__ pr_tail,
        const int* __restrict__ pr_type,
        const int* __restrict__ it_row, const int* __restrict__ it_col,
        const float* __restrict__ it_val,
        int* __restrict__ gcur,
        int* __restrict__ tkg, int2* __restrict__ tpr, int2* __restrict__ tit,
        const float2* __restrict__ user, const float2* __restrict__ ent,
        float* __restrict__ out, __half2* __restrict__ ns1) {
    __shared__ int hist[PR_NB];
    __shared__ int wbase[PR_NB];
    int g = blockIdx.x / 13;
    int r = blockIdx.x % 13;
    int tid = threadIdx.x;

    if (r < 4) {
        // ---- KG segment: block index g*4+r ----
        int bid = g * 4 + r;
        const int c0 = bid * KG_CHUNK;
        const int c1 = (c0 + KG_CHUNK < EKG) ? c0 + KG_CHUNK : EKG;
        int* gc = gcur;
        for (int k = tid; k < KG_NB; k += 256) hist[k] = 0;
        __syncthreads();
        for (int i = c0 + tid; i < c1; i += 256)
            atomicAdd(&hist[kg_head[i] >> 10], 1);
        __syncthreads();
        for (int k = tid; k < KG_NB; k += 256) {
            int c = hist[k];
            wbase[k] = (c > 0) ? atomicAdd(&gc[k], c) : 0;
            hist[k] = 0;
        }
        __syncthreads();
        for (int i = c0 + tid; i < c1; i += 256) {
            int h = kg_head[i];
            int t = kg_tail[i];
            int rr = kg_type[i];
            int bk = h >> 10;
            int l = atomicAdd(&hist[bk], 1);
            int gg = wbase[bk] + l;
            if (gg < KG_CAP)
                tkg[bk * KG_CAP + gg] = ((h & 1023) << 21) | t | ((rr - 1) << 17);
        }
    } else if (r < 8) {
        // ---- PR segment: block index g*4+(r-4) ----
        int bid = g * 4 + (r - 4);
        const int c0 = bid * PR_CHUNK;
        const int c1 = (c0 + PR_CHUNK < EPR) ? c0 + PR_CHUNK : EPR;
        int* gc = gcur + KG_NB;
        for (int k = tid; k < PR_NB; k += 256) hist[k] = 0;
        __syncthreads();
        for (int i = c0 + tid; i < c1; i += 256)
            atomicAdd(&hist[pr_head[i] >> 10], 1);
        __syncthreads();
        for (int k = tid; k < PR_NB; k += 256) {
            int c = hist[k];
            wbase[k] = (c > 0) ? atomicAdd(&gc[k], c) : 0;
            hist[k] = 0;
        }
        __syncthreads();
        for (int i = c0 + tid; i < c1; i += 256) {
            int h = pr_head[i];
            int t = pr_tail[i];
            int rr = pr_type[i];
            int bk = h >> 10;
            int l = atomicAdd(&hist[bk], 1);
            int gg = wbase[bk] + l;
            if (gg < PR_CAP)
                tpr[(size_t)bk * PR_CAP + gg] = make_int2(t | (rr << 18), h & 1023);
        }
    } else if (r < 11) {
        // ---- IT segment: block index g*3+(r-8) ----
        int bid = g * 3 + (r - 8);
        const int c0 = bid * IT_CHUNK;
        const int c1 = (c0 + IT_CHUNK < NNZI) ? c0 + IT_CHUNK : NNZI;
        int* gc = gcur + KG_NB + PR_NB;
        for (int k = tid; k < IT_NB; k += 256) hist[k] = 0;
        __syncthreads();
        for (int i = c0 + tid; i < c1; i += 256)
            atomicAdd(&hist[it_row[i] >> 10], 1);
        __syncthreads();
        for (int k = tid; k < IT_NB; k += 256) {
            int c = hist[k];
            wbase[k] = (c > 0) ? atomicAdd(&gc[k], c) : 0;
            hist[k] = 0;
        }
        __syncthreads();
        for (int i = c0 + tid; i < c1; i += 256) {
            int h = it_row[i];
            int c = it_col[i];
            float v = it_val[i];
            int bk = h >> 10;
            int l = atomicAdd(&hist[bk], 1);
            int gg = wbase[bk] + l;
            if (gg < IT_CAP)
                tit[(size_t)bk * IT_CAP + gg] =
                    make_int2(((h & 1023) << 17) | c, __float_as_int(v));
        }
    } else {
        // ---- INIT segment: block index g*2+(r-11), grid-stride streaming ----
        int bid = g * 2 + (r - 11);
        const int stride = INIT_B * 256;
        for (int i = bid * 256 + tid; i < NU * D / 2; i += stride) {
            float2 u = user[i];
            float2 e = ent[i];
            ((float2*)out)[i] = u;                                // user_res
            ((float2*)(out + NODE_BASE))[i] = u;                  // node_res user
            ((float2*)(out + NODE_BASE + NU * D))[i] = e;         // node_res entity
            ns1[i] = __floats2half2_rn(u.x, u.y);
            ns1[NU * D / 2 + i] = __floats2half2_rn(e.x, e.y);
        }
    }
}

// ---------------- bucket-count exclusive scan (3 waves) ----------------
__global__ void k_bscan(const int* __restrict__ gcur, int* __restrict__ bbase,
                        int* __restrict__ off_kg, int* __restrict__ off_pr,
                        int* __restrict__ off_it) {
    int w = threadIdx.x >> 6, lane = threadIdx.x & 63;
    const int* src; int nb, cap; int* bb; int* sent;
    if (w == 0)      { src = gcur;                 nb = KG_NB; cap = KG_CAP; bb = bbase;                 sent = off_kg + NE; }
    else if (w == 1) { src = gcur + KG_NB;         nb = PR_NB; cap = PR_CAP; bb = bbase + KG_NB;         sent = off_pr + NN; }
    else             { src = gcur + KG_NB + PR_NB; nb = IT_NB; cap = IT_CAP; bb = bbase + KG_NB + PR_NB; sent = off_it + NU; }
    int carry = 0;
    for (int b0 = 0; b0 < nb; b0 += 64) {
        int i = b0 + lane;
        int v = (i < nb) ? min(src[i], cap) : 0;
        int c = v;
        for (int d = 1; d < 64; d <<= 1) { int t = __shfl_up(c, d); if (lane >= d) c += t; }
        if (i < nb) bb[i] = carry + (c - v);
        carry += __shfl(c, 63);
    }
    if (lane == 0) *sent = carry;
}

// ---------------- pass B: bucket-local place (one block per bucket) --------
__global__ void __launch_bounds__(1024) k_bplace(
        const int* __restrict__ gcur, const int* __restrict__ bbase,
        const int* __restrict__ tkg, const int2* __restrict__ tpr,
        const int2* __restrict__ tit,
        int* __restrict__ off_kg, int* __restrict__ off_pr, int* __restrict__ off_it,
        int* __restrict__ csr_kg, int* __restrict__ csr_pr, int2* __restrict__ csr_icv) {
    __shared__ int rcnt[1024];
    __shared__ int sbuf[1024];
    int gb = blockIdx.x;
    int tid = threadIdx.x;
    int set, bid;
    if (gb < KG_NB)              { set = 0; bid = gb; }
    else if (gb < KG_NB + PR_NB) { set = 1; bid = gb - KG_NB; }
    else                         { set = 2; bid = gb - KG_NB - PR_NB; }
    int row_lo = bid << 10;
    int nrows, n, base = bbase[gb];
    const int* tbk = nullptr; const int2* tb2 = nullptr;
    if (set == 0)      { nrows = min(1024, NE - row_lo); n = min(gcur[gb], KG_CAP); tbk = tkg + (size_t)bid * KG_CAP; }
    else if (set == 1) { nrows = min(1024, NN - row_lo); n = min(gcur[gb], PR_CAP); tb2 = tpr + (size_t)bid * PR_CAP; }
    else               { nrows = min(1024, NU - row_lo); n = min(gcur[gb], IT_CAP); tb2 = tit + (size_t)bid * IT_CAP; }

    rcnt[tid] = 0;
    __syncthreads();
    if (set == 0) {
        for (int e = tid; e < n; e += 1024) atomicAdd(&rcnt[tbk[e] >> 21], 1);
    } else if (set == 1) {
        for (int e = tid; e < n; e += 1024) atomicAdd(&rcnt[tb2[e].y], 1);
    } else {
        for (int e = tid; e < n; e += 1024) atomicAdd(&rcnt[tb2[e].x >> 17], 1);
    }
    __syncthreads();
    int v = rcnt[tid];
    int x = v;
    sbuf[tid] = x;
    __syncthreads();
    for (int d = 1; d < 1024; d <<= 1) {
        int t = (tid >= d) ? sbuf[tid - d] : 0;
        __syncthreads();
        x += t;
        sbuf[tid] = x;
        __syncthreads();
    }
    int excl = x - v;
    if (tid < nrows) {
        if (set == 0)      off_kg[row_lo + tid] = base + excl;
        else if (set == 1) off_pr[row_lo + tid] = base + excl;
        else               off_it[row_lo + tid] = base + excl;
    }
    rcnt[tid] = excl;
    __syncthreads();
    if (set == 0) {
        for (int e = tid; e < n; e += 1024) {
            int vv = tbk[e];
            int p = atomicAdd(&rcnt[vv >> 21], 1);
            csr_kg[base + p] = vv & 0x1FFFFF;
        }
    } else if (set == 1) {
        for (int e = tid; e < n; e += 1024) {
            int2 vv = tb2[e];
            int p = atomicAdd(&rcnt[vv.y], 1);
            csr_pr[base + p] = vv.x;
        }
    } else {
        for (int e = tid; e < n; e += 1024) {
            int2 vv = tb2[e];
            int p = atomicAdd(&rcnt[vv.x >> 17], 1);
            csr_icv[base + p] = make_int2(vv.x & 0x1FFFF, vv.y);
        }
    }
}

// ------------- aggregation: quad-row pipelined waves ------------------------
// Each wave owns 4 consecutive rows. One coalesced load fetches all 5
// offsets; descriptor chunks for ALL FOUR rows are staged upfront (4
// independent loads in flight immediately), then rows process in order.
// 8 subs x 8 lanes per row; desc broadcast via __shfl.

#define AGG_REDUCE() \
    a0.x += __shfl_xor(a0.x, 8); a0.x += __shfl_xor(a0.x, 16); a0.x += __shfl_xor(a0.x, 32); \
    a0.y += __shfl_xor(a0.y, 8); a0.y += __shfl_xor(a0.y, 16); a0.y += __shfl_xor(a0.y, 32); \
    a0.z += __shfl_xor(a0.z, 8); a0.z += __shfl_xor(a0.z, 16); a0.z += __shfl_xor(a0.z, 32); \
    a0.w += __shfl_xor(a0.w, 8); a0.w += __shfl_xor(a0.w, 16); a0.w += __shfl_xor(a0.w, 32); \
    a1.x += __shfl_xor(a1.x, 8); a1.x += __shfl_xor(a1.x, 16); a1.x += __shfl_xor(a1.x, 32); \
    a1.y += __shfl_xor(a1.y, 8); a1.y += __shfl_xor(a1.y, 16); a1.y += __shfl_xor(a1.y, 32); \
    a1.z += __shfl_xor(a1.z, 8); a1.z += __shfl_xor(a1.z, 16); a1.z += __shfl_xor(a1.z, 32); \
    a1.w += __shfl_xor(a1.w, 8); a1.w += __shfl_xor(a1.w, 16); a1.w += __shfl_xor(a1.w, 32);

#define AGG_NORM2(n2var) \
    float n2var = a0.x * a0.x + a0.y * a0.y + a0.z * a0.z + a0.w * a0.w \
                + a1.x * a1.x + a1.y * a1.y + a1.z * a1.z + a1.w * a1.w; \
    n2var += __shfl_xor(n2var, 1); n2var += __shfl_xor(n2var, 2); n2var += __shfl_xor(n2var, 4);

__device__ __forceinline__ void ent_row(
        int row, int s, int cnt, int m0, int p0,
        int lane, int sub, int d8,
        const uint4* __restrict__ src, const float4* __restrict__ w,
        const int* __restrict__ csr,
        uint4* __restrict__ era, uint4* __restrict__ nrm_h,
        float4* __restrict__ nrm_f) {
    float4 a0 = make_float4(0.f, 0.f, 0.f, 0.f);
    float4 a1 = make_float4(0.f, 0.f, 0.f, 0.f);
    int m = m0, base = s, p = p0;
    for (;;) {
        int kmax = (m + 7) >> 3;
        for (int j = 0; j < kmax; j++) {
            int ei = (j << 3) + sub;
            int desc = __shfl(p, ei);
            if (ei < m) {
                int t = desc & 0x1FFFF; int r = desc >> 17;
                uint4 h = src[t * 8 + d8];
                float4 w0 = w[r * 16 + (d8 << 1)];
                float4 w1 = w[r * 16 + (d8 << 1) + 1];
                float4 q0 = h4_to_f4(h.x, h.y);
                float4 q1 = h4_to_f4(h.z, h.w);
                a0.x += q0.x * w0.x; a0.y += q0.y * w0.y;
                a0.z += q0.z * w0.z; a0.w += q0.w * w0.w;
                a1.x += q1.x * w1.x; a1.y += q1.y * w1.y;
                a1.z += q1.z * w1.z; a1.w += q1.w * w1.w;
            }
        }
        base += 64;
        if (base >= s + cnt) break;
        m = min(s + cnt - base, 64);
        p = (lane < m) ? csr[base + lane] : 0;
    }
    AGG_REDUCE()
    float invc = 1.f / (float)(cnt > 1 ? cnt : 1);
    a0.x *= invc; a0.y *= invc; a0.z *= invc; a0.w *= invc;
    a1.x *= invc; a1.y *= invc; a1.z *= invc; a1.w *= invc;
    AGG_NORM2(n2)
    float inr = 1.f / fmaxf(sqrtf(n2), 1e-12f);
    if (sub == 0) {
        uint2 e0 = f4_to_h4(a0);
        uint2 e1 = f4_to_h4(a1);
        era[row * 8 + d8] = make_uint4(e0.x, e0.y, e1.x, e1.y);
        float4 n0 = make_float4(a0.x * inr, a0.y * inr, a0.z * inr, a0.w * inr);
        float4 n1 = make_float4(a1.x * inr, a1.y * inr, a1.z * inr, a1.w * inr);
        if (nrm_h) {
            uint2 g0 = f4_to_h4(n0);
            uint2 g1 = f4_to_h4(n1);
            nrm_h[row * 8 + d8] = make_uint4(g0.x, g0.y, g1.x, g1.y);
        } else {
            nrm_f[row * 16 + (d8 << 1)] = n0;
            nrm_f[row * 16 + (d8 << 1) + 1] = n1;
        }
    }
}

__global__ void __launch_bounds__(256) k_agg_entity(
        const uint4* __restrict__ src, const float4* __restrict__ w,
        const int* __restrict__ off, const int* __restrict__ csr,
        uint4* __restrict__ era, uint4* __restrict__ nrm_h,
        float4* __restrict__ nrm_f) {
    int lane = threadIdx.x & 63;
    int sub = lane >> 3, d8 = lane & 7;
    int r0 = (blockIdx.x * (blockDim.x >> 6) + (threadIdx.x >> 6)) << 2;
    if (r0 >= NE) return;
    int ov = (lane <= 4) ? off[r0 + lane] : 0;
    int sA[4], cA[4], mA[4], pA[4];
#pragma unroll
    for (int i = 0; i < 4; i++) {
        sA[i] = __shfl(ov, i);
        cA[i] = __shfl(ov, i + 1) - sA[i];
        mA[i] = min(cA[i], 64);
    }
#pragma unroll
    for (int i = 0; i < 4; i++)
        pA[i] = (lane < mA[i]) ? csr[sA[i] + lane] : 0;
#pragma unroll
    for (int i = 0; i < 4; i++)
        ent_row(r0 + i, sA[i], cA[i], mA[i], pA[i], lane, sub, d8,
                src, w, csr, era, nrm_h, nrm_f);
}

__device__ __forceinline__ void node_row(
        int row, int s, int cnt, int m0, int p0,
        int lane, int sub, int d8,
        const uint4* __restrict__ src, const float4* __restrict__ ew,
        const int* __restrict__ csr,
        float4* __restrict__ node_res, uint4* __restrict__ u_out, int store_u) {
    // hoisted epilogue read: independent of the gather chain, issues first
    float4 o0 = node_res[row * 16 + (d8 << 1)];
    float4 o1 = node_res[row * 16 + (d8 << 1) + 1];
    float4 a0 = make_float4(0.f, 0.f, 0.f, 0.f);
    float4 a1 = make_float4(0.f, 0.f, 0.f, 0.f);
    int m = m0, base = s, p = p0;
    for (;;) {
        int kmax = (m + 7) >> 3;
        for (int j = 0; j < kmax; j++) {
            int ei = (j << 3) + sub;
            int desc = __shfl(p, ei);
            if (ei < m) {
                int t = desc & 0x3FFFF; int r = desc >> 18;
                uint4 h = src[(size_t)t * 8 + d8];
                float4 w0 = ew[r * 16 + (d8 << 1)];
                float4 w1 = ew[r * 16 + (d8 << 1) + 1];
                float4 q0 = h4_to_f4(h.x, h.y);
                float4 q1 = h4_to_f4(h.z, h.w);
                a0.x += q0.x * w0.x; a0.y += q0.y * w0.y;
                a0.z += q0.z * w0.z; a0.w += q0.w * w0.w;
                a1.x += q1.x * w1.x; a1.y += q1.y * w1.y;
                a1.z += q1.z * w1.z; a1.w += q1.w * w1.w;
            }
        }
        base += 64;
        if (base >= s + cnt) break;
        m = min(s + cnt - base, 64);
        p = (lane < m) ? csr[base + lane] : 0;
    }
    AGG_REDUCE()
    float invc = 1.f / (float)(cnt > 1 ? cnt : 1);
    a0.x *= invc; a0.y *= invc; a0.z *= invc; a0.w *= invc;
    a1.x *= invc; a1.y *= invc; a1.z *= invc; a1.w *= invc;
    AGG_NORM2(n2)
    float inr = 1.f / fmaxf(sqrtf(n2), 1e-12f);
    if (sub == 0) {
        float4 v0 = make_float4(a0.x * inr, a0.y * inr, a0.z * inr, a0.w * inr);
        float4 v1 = make_float4(a1.x * inr, a1.y * inr, a1.z * inr, a1.w * inr);
        o0.x += v0.x; o0.y += v0.y; o0.z += v0.z; o0.w += v0.w;
        o1.x += v1.x; o1.y += v1.y; o1.z += v1.z; o1.w += v1.w;
        node_res[row * 16 + (d8 << 1)] = o0;
        node_res[row * 16 + (d8 << 1) + 1] = o1;
        if (store_u && row < NU) {
            uint2 g0 = f4_to_h4(v0);
            uint2 g1 = f4_to_h4(v1);
            u_out[row * 8 + d8] = make_uint4(g0.x, g0.y, g1.x, g1.y);
        }
    }
}

__global__ void __launch_bounds__(256) k_agg_node(
        const uint4* __restrict__ src, const float4* __restrict__ ew,
        const int* __restrict__ off, const int* __restrict__ csr,
        float4* __restrict__ node_res,
        uint4* __restrict__ u_out, int store_u) {
    int lane = threadIdx.x & 63;
    int sub = lane >> 3, d8 = lane & 7;
    int r0 = (blockIdx.x * (blockDim.x >> 6) + (threadIdx.x >> 6)) << 2;
    if (r0 >= NN) return;
    int ov = (lane <= 4) ? off[r0 + lane] : 0;
    int sA[4], cA[4], mA[4], pA[4];
#pragma unroll
    for (int i = 0; i < 4; i++) {
        sA[i] = __shfl(ov, i);
        cA[i] = __shfl(ov, i + 1) - sA[i];
        mA[i] = min(cA[i], 64);
    }
#pragma unroll
    for (int i = 0; i < 4; i++)
        pA[i] = (lane < mA[i]) ? csr[sA[i] + lane] : 0;
#pragma unroll
    for (int i = 0; i < 4; i++)
        node_row(r0 + i, sA[i], cA[i], mA[i], pA[i], lane, sub, d8,
                 src, ew, csr, node_res, u_out, store_u);
}

__device__ __forceinline__ void user_row(
        int row, int s, int cnt, int m0, int2 p0,
        int lane, int sub, int d8,
        const uint4* __restrict__ era, const int2* __restrict__ cicv,
        float4* __restrict__ user_res) {
    // hoisted epilogue read
    float4 o0 = user_res[row * 16 + (d8 << 1)];
    float4 o1 = user_res[row * 16 + (d8 << 1) + 1];
    float4 a0 = make_float4(0.f, 0.f, 0.f, 0.f);
    float4 a1 = make_float4(0.f, 0.f, 0.f, 0.f);
    int m = m0, base = s;
    int2 p = p0;
    for (;;) {
        int kmax = (m + 7) >> 3;
        for (int j = 0; j < kmax; j++) {
            int ei = (j << 3) + sub;
            int cc = __shfl(p.x, ei);
            float vv = __shfl(__int_as_float(p.y), ei);
            if (ei < m) {
                uint4 h = era[cc * 8 + d8];
                float4 q0 = h4_to_f4(h.x, h.y);
                float4 q1 = h4_to_f4(h.z, h.w);
                a0.x += vv * q0.x; a0.y += vv * q0.y;
                a0.z += vv * q0.z; a0.w += vv * q0.w;
                a1.x += vv * q1.x; a1.y += vv * q1.y;
                a1.z += vv * q1.z; a1.w += vv * q1.w;
            }
        }
        base += 64;
        if (base >= s + cnt) break;
        m = min(s + cnt - base, 64);
        p = (lane < m) ? cicv[base + lane] : make_int2(0, 0);
    }
    AGG_REDUCE()
    AGG_NORM2(n2)
    float inr = 1.f / fmaxf(sqrtf(n2), 1e-12f);
    if (sub == 0) {
        o0.x += a0.x * inr; o0.y += a0.y * inr;
        o0.z += a0.z * inr; o0.w += a0.w * inr;
        o1.x += a1.x * inr; o1.y += a1.y * inr;
        o1.z += a1.z * inr; o1.w += a1.w * inr;
        user_res[row * 16 + (d8 << 1)] = o0;
        user_res[row * 16 + (d8 << 1) + 1] = o1;
    }
}

__global__ void __launch_bounds__(256) k_agg_user(
        const uint4* __restrict__ era, const int* __restrict__ off,
        const int2* __restrict__ cicv, float4* __restrict__ user_res) {
    int lane = threadIdx.x & 63;
    int sub = lane >> 3, d8 = lane & 7;
    int r0 = (blockIdx.x * (blockDim.x >> 6) + (threadIdx.x >> 6)) << 2;
    if (r0 >= NU) return;
    int ov = (lane <= 4) ? off[r0 + lane] : 0;
    int sA[4], cA[4], mA[4];
    int2 pA[4];
#pragma unroll
    for (int i = 0; i < 4; i++) {
        sA[i] = __shfl(ov, i);
        cA[i] = __shfl(ov, i + 1) - sA[i];
        mA[i] = min(cA[i], 64);
    }
#pragma unroll
    for (int i = 0; i < 4; i++)
        pA[i] = (lane < mA[i]) ? cicv[sA[i] + lane] : make_int2(0, 0);
#pragma unroll
    for (int i = 0; i < 4; i++)
        user_row(r0 + i, sA[i], cA[i], mA[i], pA[i], lane, sub, d8,
                 era, cicv, user_res);
}

extern "C" void kernel_launch(void* const* d_in, const int* in_sizes, int n_in,
                              void* d_out, int out_size, void* d_ws, size_t ws_size,
                              hipStream_t stream) {
    const float* user_emb     = (const float*)d_in[0];
    const float* entity_emb   = (const float*)d_in[1];
    const float* weight       = (const float*)d_in[2];
    const float* extra_weight = (const float*)d_in[3];
    const float* ivals        = (const float*)d_in[4];
    const int* edge_index     = (const int*)d_in[5];
    const int* edge_type      = (const int*)d_in[6];
    const int* xedge_index    = (const int*)d_in[7];
    const int* xedge_type     = (const int*)d_in[8];
    const int* interact_idx   = (const int*)d_in[9];
    float* out = (float*)d_out;

    const int* kg_head = edge_index;
    const int* kg_tail = edge_index + EKG;
    const int* pr_head = xedge_index;
    const int* pr_tail = xedge_index + EPR;
    const int* it_row  = interact_idx;
    const int* it_col  = interact_idx + NNZI;

    char* ws = (char*)d_ws;
    size_t ofs = 0;
    auto take = [&](size_t bytes) -> void* {
        void* p = ws + ofs;
        ofs += (bytes + 255) & ~(size_t)255;
        return p;
    };
    // fp16 source tables
    __half2* node_src1 = (__half2*)take((size_t)NN * D * 2);  // 25.6 MB, built in partA
    uint4*   era       = (uint4*)take((size_t)NE * D * 2);    // 12.8 MB fp16 raw entity means
    uint4*   node_src2 = (uint4*)take((size_t)NN * D * 2);    // 25.6 MB hop-2 table
    int* off_kg = (int*)take((NE + 1) * 4);
    int* off_pr = (int*)take((NN + 1) * 4);
    int* off_it = (int*)take((NU + 1) * 4);
    int* gcur   = (int*)take(NBALL * 4);
    int* bbase  = (int*)take(NBALL * 4);
    int* csr_kg = (int*)take((size_t)EKG * 4);
    int* csr_pr = (int*)take((size_t)EPR * 4);
    int2* csr_icv = (int2*)take((size_t)NNZI * 8);

    // temp buckets overlay era+node_src2 (38.4 MB contiguous; temps dead
    // after k_bplace, which precedes every write to era/node_src2)
    char* region2 = (char*)era;
    int*  tkg = (int*)region2;                           // 8,028,160 B
    int2* tpr = (int2*)(region2 + 8028160);              // 19,267,584 B
    int2* tit = (int2*)(region2 + 8028160 + 19267584);   // 10,436,608 B

    hipMemsetAsync(gcur, 0, NBALL * 4, stream);

    // pass A: multisplit + fused output-init (interleaved segments)
    k_partA<<<PARTA_GRID, 256, 0, stream>>>(
        kg_head, kg_tail, edge_type,
        pr_head, pr_tail, xedge_type,
        it_row, it_col, ivals,
        gcur, tkg, tpr, tit,
        (const float2*)user_emb, (const float2*)entity_emb, out, node_src1);

    k_bscan<<<1, 192, 0, stream>>>(gcur, bbase, off_kg, off_pr, off_it);

    k_bplace<<<NBALL, 1024, 0, stream>>>(gcur, bbase, tkg, tpr, tit,
                                         off_kg, off_pr, off_it,
                                         csr_kg, csr_pr, csr_icv);

    // quad-row waves: 16 rows per 256-thread block (4 waves x 4 rows)
    const float4* w4  = (const float4*)weight;
    const float4* ew4 = (const float4*)extra_weight;
    const uint4* ns1 = (const uint4*)node_src1;

    // hop 1
    k_agg_entity<<<NE / 16, 256, 0, stream>>>(
        ns1 + (size_t)NU * 8, w4, off_kg, csr_kg,
        era, node_src2 + (size_t)NU * 8, nullptr);
    k_agg_node<<<NN / 16, 256, 0, stream>>>(
        ns1, ew4, off_pr, csr_pr,
        (float4*)(out + NODE_BASE), node_src2, 1);
    k_agg_user<<<NU / 16, 256, 0, stream>>>(
        era, off_it, csr_icv, (float4*)out);

    // hop 2
    k_agg_entity<<<NE / 16, 256, 0, stream>>>(
        (const uint4*)node_src2 + (size_t)NU * 8, w4, off_kg, csr_kg,
        era, nullptr, (float4*)(out + GCN_ENT_BASE));
    k_agg_node<<<NN / 16, 256, 0, stream>>>(
        (const uint4*)node_src2, ew4, off_pr, csr_pr,
        (float4*)(out + NODE_BASE), nullptr, 0);
    k_agg_user<<<NU / 16, 256, 0, stream>>>(
        era, off_it, csr_icv, (float4*)out);
}

// Round 12
// 583.030 us; speedup vs baseline: 1.0440x; 1.0440x over previous
//
#include <hip/hip_runtime.h>
#include <hip/hip_fp16.h>

#define NU 100000      // N_USERS
#define NE 100000      // N_ENTITIES
#define NN 200000      // N_NODES
#define EKG 1500000
#define EPR 1500000
#define NNZI 1000000
#define D 64

#define GCN_ENT_BASE (NU * D)
#define NODE_BASE    (NN * D)

// ---- bucket partition config ----
#define KG_NB 98     // ceil(NE/1024)
#define PR_NB 196    // ceil(NN/1024)
#define IT_NB 98     // ceil(NU/1024)
#define NBALL (KG_NB + PR_NB + IT_NB)

#define KG_CAP 20480
#define PR_CAP 12288
#define IT_CAP 13312

#define KG_B 224
#define KG_CHUNK 6697   // 224*6697 >= EKG
#define PR_B 224
#define PR_CHUNK 6697
#define IT_B 160
#define IT_CHUNK 6250   // 160*6250 == NNZI

// ---- fp16 pack helpers (sources fp16; all math fp32) ----
__device__ __forceinline__ uint2 f4_to_h4(float4 v) {
    __half2 a = __floats2half2_rn(v.x, v.y);
    __half2 b = __floats2half2_rn(v.z, v.w);
    uint2 r;
    r.x = *(unsigned int*)&a;
    r.y = *(unsigned int*)&b;
    return r;
}
__device__ __forceinline__ float4 h4_to_f4(unsigned int lo, unsigned int hi) {
    float2 a = __half22float2(*(__half2*)&lo);
    float2 b = __half22float2(*(__half2*)&hi);
    return make_float4(a.x, a.y, b.x, b.y);
}

// ---------------- pass A: two-phase multisplit, 4-way scalar ILP -----------
// r9 profile: VALUBusy 2.5%, VGPR=12 -> each thread ran chained
// {load -> LDS atomic} round-trips with zero ILP. This version loads 4
// edges (stride 256, sentinel-guarded SCALAR loads -- no reinterpret casts)
// before issuing their 4 independent LDS atomics: dependency chain /4.
// Memory footprint and indexing identical to the verified r9 kernel.
__global__ void __launch_bounds__(256) k_partA(
        const int* __restrict__ kg_head, const int* __restrict__ kg_tail,
        const int* __restrict__ kg_type,
        const int* __restrict__ pr_head, const int* __restrict__ pr_tail,
        const int* __restrict__ pr_type,
        const int* __restrict__ it_row, const int* __restrict__ it_col,
        const float* __restrict__ it_val,
        int* __restrict__ gcur,
        int* __restrict__ tkg, int2* __restrict__ tpr, int2* __restrict__ tit) {
    __shared__ int hist[PR_NB];
    __shared__ int wbase[PR_NB];
    int bid = blockIdx.x;
    int tid = threadIdx.x;

    if (bid < KG_B) {
        const int c0 = bid * KG_CHUNK;
        const int c1 = (c0 + KG_CHUNK < EKG) ? c0 + KG_CHUNK : EKG;
        int* gc = gcur;
        for (int k = tid; k < KG_NB; k += 256) hist[k] = 0;
        __syncthreads();
        for (int i = c0 + tid; i < c1; i += 1024) {
            int iB = i + 256, iC = i + 512, iD = i + 768;
            int hA = kg_head[i];
            int hB = (iB < c1) ? kg_head[iB] : -1;
            int hC = (iC < c1) ? kg_head[iC] : -1;
            int hD = (iD < c1) ? kg_head[iD] : -1;
            atomicAdd(&hist[hA >> 10], 1);
            if (hB >= 0) atomicAdd(&hist[hB >> 10], 1);
            if (hC >= 0) atomicAdd(&hist[hC >> 10], 1);
            if (hD >= 0) atomicAdd(&hist[hD >> 10], 1);
        }
        __syncthreads();
        for (int k = tid; k < KG_NB; k += 256) {
            int c = hist[k];
            wbase[k] = (c > 0) ? atomicAdd(&gc[k], c) : 0;
            hist[k] = 0;
        }
        __syncthreads();
        for (int i = c0 + tid; i < c1; i += 1024) {
            int iB = i + 256, iC = i + 512, iD = i + 768;
            bool bB = iB < c1, bC = iC < c1, bD = iD < c1;
            int hA = kg_head[i], tA = kg_tail[i], rA = kg_type[i];
            int hB = bB ? kg_head[iB] : 0, tB = bB ? kg_tail[iB] : 0, rB = bB ? kg_type[iB] : 1;
            int hC = bC ? kg_head[iC] : 0, tC = bC ? kg_tail[iC] : 0, rC = bC ? kg_type[iC] : 1;
            int hD = bD ? kg_head[iD] : 0, tD = bD ? kg_tail[iD] : 0, rD = bD ? kg_type[iD] : 1;
            {
                int bk = hA >> 10;
                int g = wbase[bk] + atomicAdd(&hist[bk], 1);
                if (g < KG_CAP) tkg[bk * KG_CAP + g] = ((hA & 1023) << 21) | tA | ((rA - 1) << 17);
            }
            if (bB) {
                int bk = hB >> 10;
                int g = wbase[bk] + atomicAdd(&hist[bk], 1);
                if (g < KG_CAP) tkg[bk * KG_CAP + g] = ((hB & 1023) << 21) | tB | ((rB - 1) << 17);
            }
            if (bC) {
                int bk = hC >> 10;
                int g = wbase[bk] + atomicAdd(&hist[bk], 1);
                if (g < KG_CAP) tkg[bk * KG_CAP + g] = ((hC & 1023) << 21) | tC | ((rC - 1) << 17);
            }
            if (bD) {
                int bk = hD >> 10;
                int g = wbase[bk] + atomicAdd(&hist[bk], 1);
                if (g < KG_CAP) tkg[bk * KG_CAP + g] = ((hD & 1023) << 21) | tD | ((rD - 1) << 17);
            }
        }
    } else if (bid < KG_B + PR_B) {
        bid -= KG_B;
        const int c0 = bid * PR_CHUNK;
        const int c1 = (c0 + PR_CHUNK < EPR) ? c0 + PR_CHUNK : EPR;
        int* gc = gcur + KG_NB;
        for (int k = tid; k < PR_NB; k += 256) hist[k] = 0;
        __syncthreads();
        for (int i = c0 + tid; i < c1; i += 1024) {
            int iB = i + 256, iC = i + 512, iD = i + 768;
            int hA = pr_head[i];
            int hB = (iB < c1) ? pr_head[iB] : -1;
            int hC = (iC < c1) ? pr_head[iC] : -1;
            int hD = (iD < c1) ? pr_head[iD] : -1;
            atomicAdd(&hist[hA >> 10], 1);
            if (hB >= 0) atomicAdd(&hist[hB >> 10], 1);
            if (hC >= 0) atomicAdd(&hist[hC >> 10], 1);
            if (hD >= 0) atomicAdd(&hist[hD >> 10], 1);
        }
        __syncthreads();
        for (int k = tid; k < PR_NB; k += 256) {
            int c = hist[k];
            wbase[k] = (c > 0) ? atomicAdd(&gc[k], c) : 0;
            hist[k] = 0;
        }
        __syncthreads();
        for (int i = c0 + tid; i < c1; i += 1024) {
            int iB = i + 256, iC = i + 512, iD = i + 768;
            bool bB = iB < c1, bC = iC < c1, bD = iD < c1;
            int hA = pr_head[i], tA = pr_tail[i], rA = pr_type[i];
            int hB = bB ? pr_head[iB] : 0, tB = bB ? pr_tail[iB] : 0, rB = bB ? pr_type[iB] : 0;
            int hC = bC ? pr_head[iC] : 0, tC = bC ? pr_tail[iC] : 0, rC = bC ? pr_type[iC] : 0;
            int hD = bD ? pr_head[iD] : 0, tD = bD ? pr_tail[iD] : 0, rD = bD ? pr_type[iD] : 0;
            {
                int bk = hA >> 10;
                int g = wbase[bk] + atomicAdd(&hist[bk], 1);
                if (g < PR_CAP) tpr[(size_t)bk * PR_CAP + g] = make_int2(tA | (rA << 18), hA & 1023);
            }
            if (bB) {
                int bk = hB >> 10;
                int g = wbase[bk] + atomicAdd(&hist[bk], 1);
                if (g < PR_CAP) tpr[(size_t)bk * PR_CAP + g] = make_int2(tB | (rB << 18), hB & 1023);
            }
            if (bC) {
                int bk = hC >> 10;
                int g = wbase[bk] + atomicAdd(&hist[bk], 1);
                if (g < PR_CAP) tpr[(size_t)bk * PR_CAP + g] = make_int2(tC | (rC << 18), hC & 1023);
            }
            if (bD) {
                int bk = hD >> 10;
                int g = wbase[bk] + atomicAdd(&hist[bk], 1);
                if (g < PR_CAP) tpr[(size_t)bk * PR_CAP + g] = make_int2(tD | (rD << 18), hD & 1023);
            }
        }
    } else {
        bid -= KG_B + PR_B;
        const int c0 = bid * IT_CHUNK;
        const int c1 = (c0 + IT_CHUNK < NNZI) ? c0 + IT_CHUNK : NNZI;
        int* gc = gcur + KG_NB + PR_NB;
        for (int k = tid; k < IT_NB; k += 256) hist[k] = 0;
        __syncthreads();
        for (int i = c0 + tid; i < c1; i += 1024) {
            int iB = i + 256, iC = i + 512, iD = i + 768;
            int hA = it_row[i];
            int hB = (iB < c1) ? it_row[iB] : -1;
            int hC = (iC < c1) ? it_row[iC] : -1;
            int hD = (iD < c1) ? it_row[iD] : -1;
            atomicAdd(&hist[hA >> 10], 1);
            if (hB >= 0) atomicAdd(&hist[hB >> 10], 1);
            if (hC >= 0) atomicAdd(&hist[hC >> 10], 1);
            if (hD >= 0) atomicAdd(&hist[hD >> 10], 1);
        }
        __syncthreads();
        for (int k = tid; k < IT_NB; k += 256) {
            int c = hist[k];
            wbase[k] = (c > 0) ? atomicAdd(&gc[k], c) : 0;
            hist[k] = 0;
        }
        __syncthreads();
        for (int i = c0 + tid; i < c1; i += 1024) {
            int iB = i + 256, iC = i + 512, iD = i + 768;
            bool bB = iB < c1, bC = iC < c1, bD = iD < c1;
            int hA = it_row[i], cA = it_col[i];
            float vA = it_val[i];
            int hB = bB ? it_row[iB] : 0, cB = bB ? it_col[iB] : 0;
            float vB = bB ? it_val[iB] : 0.f;
            int hC = bC ? it_row[iC] : 0, cC = bC ? it_col[iC] : 0;
            float vC = bC ? it_val[iC] : 0.f;
            int hD = bD ? it_row[iD] : 0, cD = bD ? it_col[iD] : 0;
            float vD = bD ? it_val[iD] : 0.f;
            {
                int bk = hA >> 10;
                int g = wbase[bk] + atomicAdd(&hist[bk], 1);
                if (g < IT_CAP) tit[(size_t)bk * IT_CAP + g] = make_int2(((hA & 1023) << 17) | cA, __float_as_int(vA));
            }
            if (bB) {
                int bk = hB >> 10;
                int g = wbase[bk] + atomicAdd(&hist[bk], 1);
                if (g < IT_CAP) tit[(size_t)bk * IT_CAP + g] = make_int2(((hB & 1023) << 17) | cB, __float_as_int(vB));
            }
            if (bC) {
                int bk = hC >> 10;
                int g = wbase[bk] + atomicAdd(&hist[bk], 1);
                if (g < IT_CAP) tit[(size_t)bk * IT_CAP + g] = make_int2(((hC & 1023) << 17) | cC, __float_as_int(vC));
            }
            if (bD) {
                int bk = hD >> 10;
                int g = wbase[bk] + atomicAdd(&hist[bk], 1);
                if (g < IT_CAP) tit[(size_t)bk * IT_CAP + g] = make_int2(((hD & 1023) << 17) | cD, __float_as_int(vD));
            }
        }
    }
}

// ---------------- bucket-count exclusive scan (3 waves) ----------------
__global__ void k_bscan(const int* __restrict__ gcur, int* __restrict__ bbase,
                        int* __restrict__ off_kg, int* __restrict__ off_pr,
                        int* __restrict__ off_it) {
    int w = threadIdx.x >> 6, lane = threadIdx.x & 63;
    const int* src; int nb, cap; int* bb; int* sent;
    if (w == 0)      { src = gcur;                 nb = KG_NB; cap = KG_CAP; bb = bbase;                 sent = off_kg + NE; }
    else if (w == 1) { src = gcur + KG_NB;         nb = PR_NB; cap = PR_CAP; bb = bbase + KG_NB;         sent = off_pr + NN; }
    else             { src = gcur + KG_NB + PR_NB; nb = IT_NB; cap = IT_CAP; bb = bbase + KG_NB + PR_NB; sent = off_it + NU; }
    int carry = 0;
    for (int b0 = 0; b0 < nb; b0 += 64) {
        int i = b0 + lane;
        int v = (i < nb) ? min(src[i], cap) : 0;
        int c = v;
        for (int d = 1; d < 64; d <<= 1) { int t = __shfl_up(c, d); if (lane >= d) c += t; }
        if (i < nb) bb[i] = carry + (c - v);
        carry += __shfl(c, 63);
    }
    if (lane == 0) *sent = carry;
}

// ---------------- pass B: bucket-local place (one block per bucket) --------
__global__ void __launch_bounds__(1024) k_bplace(
        const int* __restrict__ gcur, const int* __restrict__ bbase,
        const int* __restrict__ tkg, const int2* __restrict__ tpr,
        const int2* __restrict__ tit,
        int* __restrict__ off_kg, int* __restrict__ off_pr, int* __restrict__ off_it,
        int* __restrict__ csr_kg, int* __restrict__ csr_pr, int2* __restrict__ csr_icv) {
    __shared__ int rcnt[1024];
    __shared__ int sbuf[1024];
    int gb = blockIdx.x;
    int tid = threadIdx.x;
    int set, bid;
    if (gb < KG_NB)              { set = 0; bid = gb; }
    else if (gb < KG_NB + PR_NB) { set = 1; bid = gb - KG_NB; }
    else                         { set = 2; bid = gb - KG_NB - PR_NB; }
    int row_lo = bid << 10;
    int nrows, n, base = bbase[gb];
    const int* tbk = nullptr; const int2* tb2 = nullptr;
    if (set == 0)      { nrows = min(1024, NE - row_lo); n = min(gcur[gb], KG_CAP); tbk = tkg + (size_t)bid * KG_CAP; }
    else if (set == 1) { nrows = min(1024, NN - row_lo); n = min(gcur[gb], PR_CAP); tb2 = tpr + (size_t)bid * PR_CAP; }
    else               { nrows = min(1024, NU - row_lo); n = min(gcur[gb], IT_CAP); tb2 = tit + (size_t)bid * IT_CAP; }

    rcnt[tid] = 0;
    __syncthreads();
    if (set == 0) {
        for (int e = tid; e < n; e += 1024) atomicAdd(&rcnt[tbk[e] >> 21], 1);
    } else if (set == 1) {
        for (int e = tid; e < n; e += 1024) atomicAdd(&rcnt[tb2[e].y], 1);
    } else {
        for (int e = tid; e < n; e += 1024) atomicAdd(&rcnt[tb2[e].x >> 17], 1);
    }
    __syncthreads();
    int v = rcnt[tid];
    int x = v;
    sbuf[tid] = x;
    __syncthreads();
    for (int d = 1; d < 1024; d <<= 1) {
        int t = (tid >= d) ? sbuf[tid - d] : 0;
        __syncthreads();
        x += t;
        sbuf[tid] = x;
        __syncthreads();
    }
    int excl = x - v;
    if (tid < nrows) {
        if (set == 0)      off_kg[row_lo + tid] = base + excl;
        else if (set == 1) off_pr[row_lo + tid] = base + excl;
        else               off_it[row_lo + tid] = base + excl;
    }
    rcnt[tid] = excl;
    __syncthreads();
    if (set == 0) {
        for (int e = tid; e < n; e += 1024) {
            int vv = tbk[e];
            int p = atomicAdd(&rcnt[vv >> 21], 1);
            csr_kg[base + p] = vv & 0x1FFFFF;
        }
    } else if (set == 1) {
        for (int e = tid; e < n; e += 1024) {
            int2 vv = tb2[e];
            int p = atomicAdd(&rcnt[vv.y], 1);
            csr_pr[base + p] = vv.x;
        }
    } else {
        for (int e = tid; e < n; e += 1024) {
            int2 vv = tb2[e];
            int p = atomicAdd(&rcnt[vv.x >> 17], 1);
            csr_icv[base + p] = make_int2(vv.x & 0x1FFFF, vv.y);
        }
    }
}

// ---------------- output init + fp16 source table build (float4) -----------
__global__ void k_init(const float4* __restrict__ user, const float4* __restrict__ ent,
                       float* __restrict__ out, uint2* __restrict__ ns1) {
    int i = blockIdx.x * blockDim.x + threadIdx.x;   // over NU*D/4
    if (i >= NU * D / 4) return;
    float4 u = user[i];
    float4 e = ent[i];
    ((float4*)out)[i] = u;                                // user_res
    ((float4*)(out + NODE_BASE))[i] = u;                  // node_res user part
    ((float4*)(out + NODE_BASE + NU * D))[i] = e;         // node_res entity part
    ns1[i] = f4_to_h4(u);                                 // node_src1 user part
    ns1[NU * D / 4 + i] = f4_to_h4(e);                    // node_src1 entity part
}

// ------------- aggregation: quad-row pipelined waves ------------------------
// Each wave owns 4 consecutive rows; all 4 rows' offset+descriptor chunks
// staged upfront; 8 subs x 8 lanes per row; desc broadcast via __shfl.

#define AGG_REDUCE() \
    a0.x += __shfl_xor(a0.x, 8); a0.x += __shfl_xor(a0.x, 16); a0.x += __shfl_xor(a0.x, 32); \
    a0.y += __shfl_xor(a0.y, 8); a0.y += __shfl_xor(a0.y, 16); a0.y += __shfl_xor(a0.y, 32); \
    a0.z += __shfl_xor(a0.z, 8); a0.z += __shfl_xor(a0.z, 16); a0.z += __shfl_xor(a0.z, 32); \
    a0.w += __shfl_xor(a0.w, 8); a0.w += __shfl_xor(a0.w, 16); a0.w += __shfl_xor(a0.w, 32); \
    a1.x += __shfl_xor(a1.x, 8); a1.x += __shfl_xor(a1.x, 16); a1.x += __shfl_xor(a1.x, 32); \
    a1.y += __shfl_xor(a1.y, 8); a1.y += __shfl_xor(a1.y, 16); a1.y += __shfl_xor(a1.y, 32); \
    a1.z += __shfl_xor(a1.z, 8); a1.z += __shfl_xor(a1.z, 16); a1.z += __shfl_xor(a1.z, 32); \
    a1.w += __shfl_xor(a1.w, 8); a1.w += __shfl_xor(a1.w, 16); a1.w += __shfl_xor(a1.w, 32);

#define AGG_NORM2(n2var) \
    float n2var = a0.x * a0.x + a0.y * a0.y + a0.z * a0.z + a0.w * a0.w \
                + a1.x * a1.x + a1.y * a1.y + a1.z * a1.z + a1.w * a1.w; \
    n2var += __shfl_xor(n2var, 1); n2var += __shfl_xor(n2var, 2); n2var += __shfl_xor(n2var, 4);

__device__ __forceinline__ void ent_row(
        int row, int s, int cnt, int m0, int p0,
        int lane, int sub, int d8,
        const uint4* __restrict__ src, const float4* __restrict__ w,
        const int* __restrict__ csr,
        uint4* __restrict__ era, uint4* __restrict__ nrm_h,
        float4* __restrict__ nrm_f) {
    float4 a0 = make_float4(0.f, 0.f, 0.f, 0.f);
    float4 a1 = make_float4(0.f, 0.f, 0.f, 0.f);
    int m = m0, base = s, p = p0;
    for (;;) {
        int kmax = (m + 7) >> 3;
        for (int j = 0; j < kmax; j++) {
            int ei = (j << 3) + sub;
            int desc = __shfl(p, ei);
            if (ei < m) {
                int t = desc & 0x1FFFF; int r = desc >> 17;
                uint4 h = src[t * 8 + d8];
                float4 w0 = w[r * 16 + (d8 << 1)];
                float4 w1 = w[r * 16 + (d8 << 1) + 1];
                float4 q0 = h4_to_f4(h.x, h.y);
                float4 q1 = h4_to_f4(h.z, h.w);
                a0.x += q0.x * w0.x; a0.y += q0.y * w0.y;
                a0.z += q0.z * w0.z; a0.w += q0.w * w0.w;
                a1.x += q1.x * w1.x; a1.y += q1.y * w1.y;
                a1.z += q1.z * w1.z; a1.w += q1.w * w1.w;
            }
        }
        base += 64;
        if (base >= s + cnt) break;
        m = min(s + cnt - base, 64);
        p = (lane < m) ? csr[base + lane] : 0;
    }
    AGG_REDUCE()
    float invc = 1.f / (float)(cnt > 1 ? cnt : 1);
    a0.x *= invc; a0.y *= invc; a0.z *= invc; a0.w *= invc;
    a1.x *= invc; a1.y *= invc; a1.z *= invc; a1.w *= invc;
    AGG_NORM2(n2)
    float inr = 1.f / fmaxf(sqrtf(n2), 1e-12f);
    if (sub == 0) {
        uint2 e0 = f4_to_h4(a0);
        uint2 e1 = f4_to_h4(a1);
        era[row * 8 + d8] = make_uint4(e0.x, e0.y, e1.x, e1.y);
        float4 n0 = make_float4(a0.x * inr, a0.y * inr, a0.z * inr, a0.w * inr);
        float4 n1 = make_float4(a1.x * inr, a1.y * inr, a1.z * inr, a1.w * inr);
        if (nrm_h) {
            uint2 g0 = f4_to_h4(n0);
            uint2 g1 = f4_to_h4(n1);
            nrm_h[row * 8 + d8] = make_uint4(g0.x, g0.y, g1.x, g1.y);
        } else {
            nrm_f[row * 16 + (d8 << 1)] = n0;
            nrm_f[row * 16 + (d8 << 1) + 1] = n1;
        }
    }
}

__global__ void __launch_bounds__(256) k_agg_entity(
        const uint4* __restrict__ src, const float4* __restrict__ w,
        const int* __restrict__ off, const int* __restrict__ csr,
        uint4* __restrict__ era, uint4* __restrict__ nrm_h,
        float4* __restrict__ nrm_f) {
    int lane = threadIdx.x & 63;
    int sub = lane >> 3, d8 = lane & 7;
    int r0 = (blockIdx.x * (blockDim.x >> 6) + (threadIdx.x >> 6)) << 2;
    if (r0 >= NE) return;
    int ov = (lane <= 4) ? off[r0 + lane] : 0;
    int sA[4], cA[4], mA[4], pA[4];
#pragma unroll
    for (int i = 0; i < 4; i++) {
        sA[i] = __shfl(ov, i);
        cA[i] = __shfl(ov, i + 1) - sA[i];
        mA[i] = min(cA[i], 64);
    }
#pragma unroll
    for (int i = 0; i < 4; i++)
        pA[i] = (lane < mA[i]) ? csr[sA[i] + lane] : 0;
#pragma unroll
    for (int i = 0; i < 4; i++)
        ent_row(r0 + i, sA[i], cA[i], mA[i], pA[i], lane, sub, d8,
                src, w, csr, era, nrm_h, nrm_f);
}

__device__ __forceinline__ void node_row(
        int row, int s, int cnt, int m0, int p0,
        int lane, int sub, int d8,
        const uint4* __restrict__ src, const float4* __restrict__ ew,
        const int* __restrict__ csr,
        float4* __restrict__ node_res, uint4* __restrict__ u_out, int store_u) {
    // hoisted epilogue read: independent of the gather chain, issues first
    float4 o0 = node_res[row * 16 + (d8 << 1)];
    float4 o1 = node_res[row * 16 + (d8 << 1) + 1];
    float4 a0 = make_float4(0.f, 0.f, 0.f, 0.f);
    float4 a1 = make_float4(0.f, 0.f, 0.f, 0.f);
    int m = m0, base = s, p = p0;
    for (;;) {
        int kmax = (m + 7) >> 3;
        for (int j = 0; j < kmax; j++) {
            int ei = (j << 3) + sub;
            int desc = __shfl(p, ei);
            if (ei < m) {
                int t = desc & 0x3FFFF; int r = desc >> 18;
                uint4 h = src[(size_t)t * 8 + d8];
                float4 w0 = ew[r * 16 + (d8 << 1)];
                float4 w1 = ew[r * 16 + (d8 << 1) + 1];
                float4 q0 = h4_to_f4(h.x, h.y);
                float4 q1 = h4_to_f4(h.z, h.w);
                a0.x += q0.x * w0.x; a0.y += q0.y * w0.y;
                a0.z += q0.z * w0.z; a0.w += q0.w * w0.w;
                a1.x += q1.x * w1.x; a1.y += q1.y * w1.y;
                a1.z += q1.z * w1.z; a1.w += q1.w * w1.w;
            }
        }
        base += 64;
        if (base >= s + cnt) break;
        m = min(s + cnt - base, 64);
        p = (lane < m) ? csr[base + lane] : 0;
    }
    AGG_REDUCE()
    float invc = 1.f / (float)(cnt > 1 ? cnt : 1);
    a0.x *= invc; a0.y *= invc; a0.z *= invc; a0.w *= invc;
    a1.x *= invc; a1.y *= invc; a1.z *= invc; a1.w *= invc;
    AGG_NORM2(n2)
    float inr = 1.f / fmaxf(sqrtf(n2), 1e-12f);
    if (sub == 0) {
        float4 v0 = make_float4(a0.x * inr, a0.y * inr, a0.z * inr, a0.w * inr);
        float4 v1 = make_float4(a1.x * inr, a1.y * inr, a1.z * inr, a1.w * inr);
        o0.x += v0.x; o0.y += v0.y; o0.z += v0.z; o0.w += v0.w;
        o1.x += v1.x; o1.y += v1.y; o1.z += v1.z; o1.w += v1.w;
        node_res[row * 16 + (d8 << 1)] = o0;
        node_res[row * 16 + (d8 << 1) + 1] = o1;
        if (store_u && row < NU) {
            uint2 g0 = f4_to_h4(v0);
            uint2 g1 = f4_to_h4(v1);
            u_out[row * 8 + d8] = make_uint4(g0.x, g0.y, g1.x, g1.y);
        }
    }
}

__global__ void __launch_bounds__(256) k_agg_node(
        const uint4* __restrict__ src, const float4* __restrict__ ew,
        const int* __restrict__ off, const int* __restrict__ csr,
        float4* __restrict__ node_res,
        uint4* __restrict__ u_out, int store_u) {
    int lane = threadIdx.x & 63;
    int sub = lane >> 3, d8 = lane & 7;
    int r0 = (blockIdx.x * (blockDim.x >> 6) + (threadIdx.x >> 6)) << 2;
    if (r0 >= NN) return;
    int ov = (lane <= 4) ? off[r0 + lane] : 0;
    int sA[4], cA[4], mA[4], pA[4];
#pragma unroll
    for (int i = 0; i < 4; i++) {
        sA[i] = __shfl(ov, i);
        cA[i] = __shfl(ov, i + 1) - sA[i];
        mA[i] = min(cA[i], 64);
    }
#pragma unroll
    for (int i = 0; i < 4; i++)
        pA[i] = (lane < mA[i]) ? csr[sA[i] + lane] : 0;
#pragma unroll
    for (int i = 0; i < 4; i++)
        node_row(r0 + i, sA[i], cA[i], mA[i], pA[i], lane, sub, d8,
                 src, ew, csr, node_res, u_out, store_u);
}

__device__ __forceinline__ void user_row(
        int row, int s, int cnt, int m0, int2 p0,
        int lane, int sub, int d8,
        const uint4* __restrict__ era, const int2* __restrict__ cicv,
        float4* __restrict__ user_res) {
    // hoisted epilogue read
    float4 o0 = user_res[row * 16 + (d8 << 1)];
    float4 o1 = user_res[row * 16 + (d8 << 1) + 1];
    float4 a0 = make_float4(0.f, 0.f, 0.f, 0.f);
    float4 a1 = make_float4(0.f, 0.f, 0.f, 0.f);
    int m = m0, base = s;
    int2 p = p0;
    for (;;) {
        int kmax = (m + 7) >> 3;
        for (int j = 0; j < kmax; j++) {
            int ei = (j << 3) + sub;
            int cc = __shfl(p.x, ei);
            float vv = __shfl(__int_as_float(p.y), ei);
            if (ei < m) {
                uint4 h = era[cc * 8 + d8];
                float4 q0 = h4_to_f4(h.x, h.y);
                float4 q1 = h4_to_f4(h.z, h.w);
                a0.x += vv * q0.x; a0.y += vv * q0.y;
                a0.z += vv * q0.z; a0.w += vv * q0.w;
                a1.x += vv * q1.x; a1.y += vv * q1.y;
                a1.z += vv * q1.z; a1.w += vv * q1.w;
            }
        }
        base += 64;
        if (base >= s + cnt) break;
        m = min(s + cnt - base, 64);
        p = (lane < m) ? cicv[base + lane] : make_int2(0, 0);
    }
    AGG_REDUCE()
    AGG_NORM2(n2)
    float inr = 1.f / fmaxf(sqrtf(n2), 1e-12f);
    if (sub == 0) {
        o0.x += a0.x * inr; o0.y += a0.y * inr;
        o0.z += a0.z * inr; o0.w += a0.w * inr;
        o1.x += a1.x * inr; o1.y += a1.y * inr;
        o1.z += a1.z * inr; o1.w += a1.w * inr;
        user_res[row * 16 + (d8 << 1)] = o0;
        user_res[row * 16 + (d8 << 1) + 1] = o1;
    }
}

__global__ void __launch_bounds__(256) k_agg_user(
        const uint4* __restrict__ era, const int* __restrict__ off,
        const int2* __restrict__ cicv, float4* __restrict__ user_res) {
    int lane = threadIdx.x & 63;
    int sub = lane >> 3, d8 = lane & 7;
    int r0 = (blockIdx.x * (blockDim.x >> 6) + (threadIdx.x >> 6)) << 2;
    if (r0 >= NU) return;
    int ov = (lane <= 4) ? off[r0 + lane] : 0;
    int sA[4], cA[4], mA[4];
    int2 pA[4];
#pragma unroll
    for (int i = 0; i < 4; i++) {
        sA[i] = __shfl(ov, i);
        cA[i] = __shfl(ov, i + 1) - sA[i];
        mA[i] = min(cA[i], 64);
    }
#pragma unroll
    for (int i = 0; i < 4; i++)
        pA[i] = (lane < mA[i]) ? cicv[sA[i] + lane] : make_int2(0, 0);
#pragma unroll
    for (int i = 0; i < 4; i++)
        user_row(r0 + i, sA[i], cA[i], mA[i], pA[i], lane, sub, d8,
                 era, cicv, user_res);
}

extern "C" void kernel_launch(void* const* d_in, const int* in_sizes, int n_in,
                              void* d_out, int out_size, void* d_ws, size_t ws_size,
                              hipStream_t stream) {
    const float* user_emb     = (const float*)d_in[0];
    const float* entity_emb   = (const float*)d_in[1];
    const float* weight       = (const float*)d_in[2];
    const float* extra_weight = (const float*)d_in[3];
    const float* ivals        = (const float*)d_in[4];
    const int* edge_index     = (const int*)d_in[5];
    const int* edge_type      = (const int*)d_in[6];
    const int* xedge_index    = (const int*)d_in[7];
    const int* xedge_type     = (const int*)d_in[8];
    const int* interact_idx   = (const int*)d_in[9];
    float* out = (float*)d_out;

    const int* kg_head = edge_index;
    const int* kg_tail = edge_index + EKG;
    const int* pr_head = xedge_index;
    const int* pr_tail = xedge_index + EPR;
    const int* it_row  = interact_idx;
    const int* it_col  = interact_idx + NNZI;

    char* ws = (char*)d_ws;
    size_t ofs = 0;
    auto take = [&](size_t bytes) -> void* {
        void* p = ws + ofs;
        ofs += (bytes + 255) & ~(size_t)255;
        return p;
    };
    // fp16 source tables
    __half2* node_src1 = (__half2*)take((size_t)NN * D * 2);  // 25.6 MB, built by k_init
    uint4*   era       = (uint4*)take((size_t)NE * D * 2);    // 12.8 MB fp16 raw entity means
    uint4*   node_src2 = (uint4*)take((size_t)NN * D * 2);    // 25.6 MB hop-2 table
    int* off_kg = (int*)take((NE + 1) * 4);
    int* off_pr = (int*)take((NN + 1) * 4);
    int* off_it = (int*)take((NU + 1) * 4);
    int* gcur   = (int*)take(NBALL * 4);
    int* bbase  = (int*)take(NBALL * 4);
    int* csr_kg = (int*)take((size_t)EKG * 4);
    int* csr_pr = (int*)take((size_t)EPR * 4);
    int2* csr_icv = (int2*)take((size_t)NNZI * 8);

    // temp buckets overlay era+node_src2 (38.4 MB contiguous; temps dead
    // after k_bplace, which precedes every write to era/node_src2)
    char* region2 = (char*)era;
    int*  tkg = (int*)region2;                           // 8,028,160 B
    int2* tpr = (int2*)(region2 + 8028160);              // 19,267,584 B
    int2* tit = (int2*)(region2 + 8028160 + 19267584);   // 10,436,608 B

    hipMemsetAsync(gcur, 0, NBALL * 4, stream);

    k_partA<<<KG_B + PR_B + IT_B, 256, 0, stream>>>(
        kg_head, kg_tail, edge_type,
        pr_head, pr_tail, xedge_type,
        it_row, it_col, ivals,
        gcur, tkg, tpr, tit);

    k_bscan<<<1, 192, 0, stream>>>(gcur, bbase, off_kg, off_pr, off_it);

    k_bplace<<<NBALL, 1024, 0, stream>>>(gcur, bbase, tkg, tpr, tit,
                                         off_kg, off_pr, off_it,
                                         csr_kg, csr_pr, csr_icv);

    // init residual accumulators in d_out + build fp16 hop-1 source table
    k_init<<<(NU * D / 4 + 255) / 256, 256, 0, stream>>>(
        (const float4*)user_emb, (const float4*)entity_emb, out, (uint2*)node_src1);

    // quad-row waves: 16 rows per 256-thread block (4 waves x 4 rows)
    const float4* w4  = (const float4*)weight;
    const float4* ew4 = (const float4*)extra_weight;
    const uint4* ns1 = (const uint4*)node_src1;

    // hop 1
    k_agg_entity<<<NE / 16, 256, 0, stream>>>(
        ns1 + (size_t)NU * 8, w4, off_kg, csr_kg,
        era, node_src2 + (size_t)NU * 8, nullptr);
    k_agg_node<<<NN / 16, 256, 0, stream>>>(
        ns1, ew4, off_pr, csr_pr,
        (float4*)(out + NODE_BASE), node_src2, 1);
    k_agg_user<<<NU / 16, 256, 0, stream>>>(
        era, off_it, csr_icv, (float4*)out);

    // hop 2
    k_agg_entity<<<NE / 16, 256, 0, stream>>>(
        (const uint4*)node_src2 + (size_t)NU * 8, w4, off_kg, csr_kg,
        era, nullptr, (float4*)(out + GCN_ENT_BASE));
    k_agg_node<<<NN / 16, 256, 0, stream>>>(
        (const uint4*)node_src2, ew4, off_pr, csr_pr,
        (float4*)(out + NODE_BASE), nullptr, 0);
    k_agg_user<<<NU / 16, 256, 0, stream>>>(
        era, off_it, csr_icv, (float4*)out);
}